// Round 10
// baseline (299.347 us; speedup 1.0000x reference)
//
#include <hip/hip_runtime.h>
#include <hip/hip_bf16.h>

#define HID 128
#define IN_DIM 16

typedef short bf16x8 __attribute__((ext_vector_type(8)));
typedef float f32x4 __attribute__((ext_vector_type(4)));
typedef unsigned short u16x8 __attribute__((ext_vector_type(8)));

// ---------- bf16 helpers (RNE) ----------
__device__ __forceinline__ unsigned short f2bf(float f) {
    unsigned int u = __float_as_uint(f);
    unsigned int r = (u + 0x7FFFu + ((u >> 16) & 1u)) >> 16;
    return (unsigned short)r;
}
__device__ __forceinline__ float bf2f(unsigned short u) {
    return __uint_as_float(((unsigned int)u) << 16);
}

// ---------------- zero words (indeg [int] + pooled [float], adjacent) ----------------
__global__ __launch_bounds__(256) void k_zero_words(unsigned int* p, int n) {
    int i = blockIdx.x * blockDim.x + threadIdx.x;
    if (i < n) p[i] = 0u;
}

// ---------------- B1: indeg atomics + per-block bucket histogram ----------------
__global__ __launch_bounds__(256) void k_hist_count(const int* __restrict__ dst,
                                                    int* __restrict__ indeg,
                                                    int* __restrict__ hist,
                                                    int E, int NB, int chunk) {
    __shared__ int lh[256];
    for (int i = threadIdx.x; i < NB; i += 256) lh[i] = 0;
    __syncthreads();
    int s0 = blockIdx.x * chunk;
    int e_end = min(E, s0 + chunk);
    for (int e = s0 + threadIdx.x; e < e_end; e += 256) {
        int d = dst[e];
        atomicAdd(&indeg[d], 1);
        atomicAdd(&lh[d >> 8], 1);
    }
    __syncthreads();
    for (int i = threadIdx.x; i < NB; i += 256)
        hist[blockIdx.x * NB + i] = lh[i];   // [blk][b] contiguous per block
}

// ---------------- 2-level exclusive scan over indeg ----------------
__global__ __launch_bounds__(256) void k_scan1(const int* __restrict__ indeg, int* __restrict__ offs,
                                               int* __restrict__ blocksum, int N) {
    __shared__ int sdata[256];
    int base = blockIdx.x * 1024 + threadIdx.x * 4;
    int v0 = (base + 0 < N) ? indeg[base + 0] : 0;
    int v1 = (base + 1 < N) ? indeg[base + 1] : 0;
    int v2 = (base + 2 < N) ? indeg[base + 2] : 0;
    int v3 = (base + 3 < N) ? indeg[base + 3] : 0;
    int s = v0 + v1 + v2 + v3;
    sdata[threadIdx.x] = s;
    __syncthreads();
    for (int off = 1; off < 256; off <<= 1) {
        int t = (threadIdx.x >= off) ? sdata[threadIdx.x - off] : 0;
        __syncthreads();
        sdata[threadIdx.x] += t;
        __syncthreads();
    }
    int excl = sdata[threadIdx.x] - s;
    if (base + 0 < N) offs[base + 0] = excl;  excl += v0;
    if (base + 1 < N) offs[base + 1] = excl;  excl += v1;
    if (base + 2 < N) offs[base + 2] = excl;  excl += v2;
    if (base + 3 < N) offs[base + 3] = excl;
    if (threadIdx.x == 255) blocksum[blockIdx.x] = sdata[255];
}

// ---------------- fused: blocksum scan | per-graph counts | W2T | hist 2D-scan ----------------
__global__ __launch_bounds__(256) void k_scan2_aux(int* __restrict__ blocksum, int nblk,
                                                   const int* __restrict__ batch, float* __restrict__ cnt,
                                                   const float* __restrict__ W2,
                                                   unsigned short* __restrict__ W2T,
                                                   int* __restrict__ hist, int* __restrict__ bucket_base,
                                                   int N, int G, int NB, int E) {
    int bid = blockIdx.x;
    if (bid == 0) {
        // wave-parallel exclusive scan of blocksum (nblk <= 64 fast path)
        int lane = threadIdx.x;
        if (lane < 64) {
            if (nblk <= 64) {
                int orig = (lane < nblk) ? blocksum[lane] : 0;
                int v = orig;
                #pragma unroll
                for (int off = 1; off < 64; off <<= 1) {
                    int t = __shfl_up(v, off, 64);
                    if (lane >= off) v += t;
                }
                if (lane < nblk) blocksum[lane] = v - orig;
            } else if (lane == 0) {
                int acc = 0;
                for (int i = 0; i < nblk; ++i) { int t = blocksum[i]; blocksum[i] = acc; acc += t; }
            }
        }
    } else if (bid == 1) {
        int g = threadIdx.x;
        if (g >= G) return;
        int lo = 0, hi = N;
        while (lo < hi) { int mid = (lo + hi) >> 1; if (batch[mid] < g) lo = mid + 1; else hi = mid; }
        int start = lo;
        lo = 0; hi = N;
        while (lo < hi) { int mid = (lo + hi) >> 1; if (batch[mid] <= g) lo = mid + 1; else hi = mid; }
        cnt[g] = (float)(lo - start);
    } else if (bid < 66) {
        int t = (bid - 2) * 256 + threadIdx.x;   // 0..16383
        int n = t >> 7, k = t & 127;
        W2T[t] = f2bf(W2[(size_t)k * HID + n]);
    } else {
        // B2: column scan of hist[blk][b] over blk, then bucket bases
        __shared__ int btot[256];
        __shared__ int bbase[256];
        int b = threadIdx.x;
        if (b < NB) {
            int s = 0;
            for (int blk = 0; blk < 256; ++blk) {
                int idx = blk * NB + b;
                int t = hist[idx];
                hist[idx] = s;
                s += t;
            }
            btot[b] = s;
        }
        __syncthreads();
        if (threadIdx.x == 0) {
            int acc = 0;
            for (int bb = 0; bb < NB; ++bb) { bbase[bb] = acc; acc += btot[bb]; }
        }
        __syncthreads();
        if (b < NB) {
            int base = bbase[b];
            bucket_base[b] = base;
            for (int blk = 0; blk < 256; ++blk) hist[blk * NB + b] += base;
        }
        if (threadIdx.x == 0) bucket_base[NB] = E;
    }
}

// scan finalize + dinv + xs16 = bf16(dinv*x)  (fused)
__global__ __launch_bounds__(256) void k_scan3(int* __restrict__ offs,
                                               const int* __restrict__ blocksum,
                                               const int* __restrict__ indeg,
                                               float* __restrict__ dinv,
                                               const float* __restrict__ x,
                                               unsigned short* __restrict__ xs16, int N) {
    int i = blockIdx.x * blockDim.x + threadIdx.x;
    if (i >= N) return;
    offs[i] += blocksum[i >> 10];
    float di = rsqrtf(1.0f + (float)indeg[i]);
    dinv[i] = di;
    #pragma unroll
    for (int q = 0; q < 4; ++q) {
        float4 v = *reinterpret_cast<const float4*>(x + (size_t)i * IN_DIM + q * 4);
        ushort4 o4;
        o4.x = f2bf(di * v.x); o4.y = f2bf(di * v.y);
        o4.z = f2bf(di * v.z); o4.w = f2bf(di * v.w);
        *reinterpret_cast<ushort4*>(xs16 + (size_t)i * IN_DIM + q * 4) = o4;
    }
}

// ---------------- B3: scatter packed edges into bucket-grouped array ----------------
__global__ __launch_bounds__(256) void k_bucket(const int* __restrict__ src, const int* __restrict__ dst,
                                                const int* __restrict__ hist,
                                                unsigned int* __restrict__ bucketed,
                                                int E, int NB, int chunk) {
    __shared__ int lcur[256];
    for (int i = threadIdx.x; i < NB; i += 256) lcur[i] = hist[blockIdx.x * NB + i];
    __syncthreads();
    int s0 = blockIdx.x * chunk;
    int e_end = min(E, s0 + chunk);
    for (int e = s0 + threadIdx.x; e < e_end; e += 256) {
        int d = dst[e], s = src[e];
        int p = atomicAdd(&lcur[d >> 8], 1);
        bucketed[p] = ((unsigned int)d << 16) | (unsigned int)s;
    }
}

// ---------------- B4: per-bucket CSR fill (one block per 256-node bucket) ----------------
__global__ __launch_bounds__(256) void k_fill2(const unsigned int* __restrict__ bucketed,
                                               const int* __restrict__ bucket_base,
                                               const int* __restrict__ offs,
                                               unsigned short* __restrict__ csr, int N) {
    __shared__ int lcur[256];
    int n0 = blockIdx.x << 8;
    int t = threadIdx.x;
    lcur[t] = (n0 + t < N) ? offs[n0 + t] : 0;
    __syncthreads();
    int bb = bucket_base[blockIdx.x], be = bucket_base[blockIdx.x + 1];
    for (int e = bb + t; e < be; e += 256) {
        unsigned int u = bucketed[e];
        int d = (int)(u >> 16), s = (int)(u & 0xFFFFu);
        int p = atomicAdd(&lcur[d - n0], 1);
        csr[p] = (unsigned short)s;
    }
}

// ---------------- gather16: y[i] = xs16[i] + sum_j xs16[j]   (2 thr/node, ushort8, unroll 8) ----------------
__global__ __launch_bounds__(256) void k_gather16(const unsigned short* __restrict__ xs16,
                                                  const int* __restrict__ offs,
                                                  const int* __restrict__ indeg,
                                                  const unsigned short* __restrict__ csr,
                                                  float* __restrict__ y, int N) {
    int t = blockIdx.x * 256 + threadIdx.x;
    int node = t >> 1;
    if (node >= N) return;
    int c = (t & 1) * 8;
    int base = offs[node], deg = indeg[node];
    u16x8 ow = *reinterpret_cast<const u16x8*>(xs16 + (size_t)node * IN_DIM + c);
    float a[8];
    #pragma unroll
    for (int d = 0; d < 8; ++d) a[d] = bf2f(ow[d]);
    int j = 0;
    for (; j + 8 <= deg; j += 8) {
        int sI[8];
        #pragma unroll
        for (int u = 0; u < 8; ++u) sI[u] = csr[base + j + u];
        u16x8 v[8];
        #pragma unroll
        for (int u = 0; u < 8; ++u)
            v[u] = *reinterpret_cast<const u16x8*>(xs16 + (size_t)sI[u] * IN_DIM + c);
        #pragma unroll
        for (int u = 0; u < 8; ++u)
            #pragma unroll
            for (int d = 0; d < 8; ++d) a[d] += bf2f(v[u][d]);
    }
    for (; j < deg; ++j) {
        int s = csr[base + j];
        u16x8 v = *reinterpret_cast<const u16x8*>(xs16 + (size_t)s * IN_DIM + c);
        #pragma unroll
        for (int d = 0; d < 8; ++d) a[d] += bf2f(v[d]);
    }
    float* yp = y + (size_t)node * IN_DIM + c;
    *reinterpret_cast<float4*>(yp + 0) = make_float4(a[0], a[1], a[2], a[3]);
    *reinterpret_cast<float4*>(yp + 4) = make_float4(a[4], a[5], a[6], a[7]);
}

// ---------------- GEMM1b: h1p[i] = bf16(dinv_i * relu(dinv_i*(y[i]@W1) + b1)) ----------------
__global__ __launch_bounds__(256) void k_gemm1b(const float* __restrict__ y,
                                                const float* __restrict__ W1,
                                                const float* __restrict__ dinv,
                                                const float* __restrict__ b1,
                                                unsigned short* __restrict__ out, int N) {
    __shared__ float Ws[IN_DIM * HID];   // 8 KB
    __shared__ float xs[8][IN_DIM];      // 512 B
    int nb = blockIdx.x * 8;
    for (int i = threadIdx.x * 4; i < IN_DIM * HID; i += 256 * 4)
        *reinterpret_cast<float4*>(&Ws[i]) = *reinterpret_cast<const float4*>(&W1[i]);
    int nrows = min(8, N - nb);
    if (threadIdx.x < 32) {
        int r = threadIdx.x >> 2, c = (threadIdx.x & 3) * 4;
        if (r < nrows)
            *reinterpret_cast<float4*>(&xs[r][c]) =
                *reinterpret_cast<const float4*>(&y[(size_t)(nb + r) * IN_DIM + c]);
    }
    __syncthreads();
    int f = threadIdx.x & 127;
    int g = threadIdx.x >> 7;
    float bb = b1[f];
    for (int r = g; r < nrows; r += 2) {
        int node = nb + r;
        float acc = 0.f;
        #pragma unroll
        for (int k = 0; k < IN_DIM; ++k) acc += xs[r][k] * Ws[k * HID + f];
        float di = dinv[node];
        out[(size_t)node * HID + f] = f2bf(di * fmaxf(di * acc + bb, 0.f));
    }
}

// ---------------- gather_z: z[i] = h1p[i] + sum_j h1p[j]  (16 thr/node, ushort8, unroll 8) ----------------
__global__ __launch_bounds__(256) void k_gather_z(const unsigned short* __restrict__ h1p,
                                                  const int* __restrict__ offs,
                                                  const int* __restrict__ indeg,
                                                  const unsigned short* __restrict__ csr,
                                                  unsigned short* __restrict__ z, int N) {
    int t = blockIdx.x * 256 + threadIdx.x;
    int node = t >> 4;
    if (node >= N) return;
    int c = (t & 15) * 8;
    int base = offs[node], deg = indeg[node];
    u16x8 ow = *reinterpret_cast<const u16x8*>(h1p + (size_t)node * HID + c);
    float a[8];
    #pragma unroll
    for (int d = 0; d < 8; ++d) a[d] = bf2f(ow[d]);
    int j = 0;
    for (; j + 8 <= deg; j += 8) {
        int sI[8];
        #pragma unroll
        for (int u = 0; u < 8; ++u) sI[u] = csr[base + j + u];
        u16x8 v[8];
        #pragma unroll
        for (int u = 0; u < 8; ++u)
            v[u] = *reinterpret_cast<const u16x8*>(h1p + (size_t)sI[u] * HID + c);
        #pragma unroll
        for (int u = 0; u < 8; ++u)
            #pragma unroll
            for (int d = 0; d < 8; ++d) a[d] += bf2f(v[u][d]);
    }
    for (; j < deg; ++j) {
        int s = csr[base + j];
        u16x8 v = *reinterpret_cast<const u16x8*>(h1p + (size_t)s * HID + c);
        #pragma unroll
        for (int d = 0; d < 8; ++d) a[d] += bf2f(v[d]);
    }
    u16x8 o;
    #pragma unroll
    for (int d = 0; d < 8; ++d) o[d] = f2bf(a[d]);
    *reinterpret_cast<u16x8*>(z + (size_t)node * HID + c) = o;
}

// ---------------- GEMM2-MFMA + fused mean-pool ----------------
// mfma_f32_16x16x32_bf16: A row=lane&15,k=(lane>>4)*8+j; D col=lane&15,row=(lane>>4)*4+reg [m89]
__global__ __launch_bounds__(256) void k_gemm2_pool(const unsigned short* __restrict__ z,
                                                    const unsigned short* __restrict__ W2T,
                                                    const float* __restrict__ dinv,
                                                    const float* __restrict__ b2,
                                                    const int* __restrict__ batch,
                                                    float* __restrict__ pooled, int N) {
    __shared__ float pool_s[HID];
    int wave = threadIdx.x >> 6;
    int lane = threadIdx.x & 63;
    int R = blockIdx.x * 64 + wave * 16;
    int lr = lane & 15;
    int lk = (lane >> 4) * 8;
    f32x4 acc[8] = {};
    const unsigned short* arow = z + (size_t)(R + lr) * HID;
    #pragma unroll
    for (int kk = 0; kk < 4; ++kk) {
        bf16x8 a = *reinterpret_cast<const bf16x8*>(arow + kk * 32 + lk);
        #pragma unroll
        for (int cf = 0; cf < 8; ++cf) {
            bf16x8 b = *reinterpret_cast<const bf16x8*>(W2T + (size_t)(cf * 16 + lr) * HID + kk * 32 + lk);
            acc[cf] = __builtin_amdgcn_mfma_f32_16x16x32_bf16(a, b, acc[cf], 0, 0, 0);
        }
    }
    int r0 = (lane >> 4) * 4;
    float di[4];
    int nd[4];
    #pragma unroll
    for (int r = 0; r < 4; ++r) {
        nd[r] = R + r0 + r;
        di[r] = (nd[r] < N) ? dinv[nd[r]] : 0.f;
    }
    int R0 = blockIdx.x * 64;
    int gid0 = batch[min(R0, N - 1)];
    bool single = (R0 + 63 < N) && (batch[R0 + 63] == gid0);
    if (single) {
        if (threadIdx.x < HID) pool_s[threadIdx.x] = 0.f;
        __syncthreads();
        #pragma unroll
        for (int cf = 0; cf < 8; ++cf) {
            float bb = b2[cf * 16 + lr];
            float sc = 0.f;
            #pragma unroll
            for (int r = 0; r < 4; ++r)
                sc += fmaxf(di[r] * acc[cf][r] + bb, 0.f);
            sc += __shfl_xor(sc, 16);
            sc += __shfl_xor(sc, 32);
            if (lane < 16) atomicAdd(&pool_s[cf * 16 + lr], sc);
        }
        __syncthreads();
        if (threadIdx.x < HID)
            atomicAdd(&pooled[(size_t)gid0 * HID + threadIdx.x], pool_s[threadIdx.x]);
    } else {
        #pragma unroll
        for (int r = 0; r < 4; ++r) {
            if (nd[r] < N) {
                int bi = batch[nd[r]];
                #pragma unroll
                for (int cf = 0; cf < 8; ++cf) {
                    float v = fmaxf(di[r] * acc[cf][r] + b2[cf * 16 + lr], 0.f);
                    atomicAdd(&pooled[(size_t)bi * HID + cf * 16 + lr], v);
                }
            }
        }
    }
}

// ---------------- final FC ----------------
__global__ __launch_bounds__(256) void k_fc(const float* __restrict__ pooled,
                                            const float* __restrict__ cnt,
                                            const float* __restrict__ Wfc,
                                            const float* __restrict__ bfc,
                                            float* __restrict__ out, int G, int O) {
    int t = blockIdx.x * blockDim.x + threadIdx.x;
    if (t >= G * O) return;
    int g = t / O, o = t % O;
    float acc = 0.f;
    for (int k = 0; k < HID; ++k) acc += pooled[(size_t)g * HID + k] * Wfc[(size_t)k * O + o];
    out[t] = acc / fmaxf(cnt[g], 1.f) + bfc[o];
}

extern "C" void kernel_launch(void* const* d_in, const int* in_sizes, int n_in,
                              void* d_out, int out_size, void* d_ws, size_t ws_size,
                              hipStream_t stream) {
    const float* x     = (const float*)d_in[0];
    const int*   ei    = (const int*)d_in[1];
    const int*   batch = (const int*)d_in[2];
    const float* W1    = (const float*)d_in[3];
    const float* b1    = (const float*)d_in[4];
    const float* W2    = (const float*)d_in[5];
    const float* b2    = (const float*)d_in[6];
    const float* Wfc   = (const float*)d_in[7];
    const float* bfc   = (const float*)d_in[8];
    float* out = (float*)d_out;

    const int E = in_sizes[1] / 2;
    const int N = in_sizes[2];
    const int O = in_sizes[8];              // 16
    const int G = out_size / O;             // 64
    const int Npad = ((N + 63) / 64) * 64;
    const int NB = (N + 255) >> 8;          // 256-node buckets
    const int CHUNK = (E + 255) / 256;      // edges per B1/B3 block

    const int* src = ei;
    const int* dst = ei + E;

    // workspace layout (all segment starts 16B-aligned for these sizes)
    char* ws = (char*)d_ws;
    int*   indeg  = (int*)ws;                        ws += sizeof(int) * N;
    float* pooled = (float*)ws;                      ws += sizeof(float) * G * HID;
    float* dinv   = (float*)ws;                      ws += sizeof(float) * N;
    int*   offs   = (int*)ws;                        ws += sizeof(int) * N;
    int*   hist   = (int*)ws;                        ws += sizeof(int) * 256 * NB;
    int*   bucket_base = (int*)ws;                   ws += sizeof(int) * ((NB + 4) & ~3);
    int*   blocksum = (int*)ws;                      ws += sizeof(int) * 256;
    float* cnt    = (float*)ws;                      ws += sizeof(float) * G;
    float* y      = (float*)ws;                      ws += sizeof(float) * (size_t)N * IN_DIM;
    unsigned short* xs16 = (unsigned short*)ws;      ws += sizeof(unsigned short) * (size_t)N * IN_DIM;
    unsigned short* w2t  = (unsigned short*)ws;      ws += sizeof(unsigned short) * (size_t)HID * HID;
    unsigned short* h1p  = (unsigned short*)ws;      ws += sizeof(unsigned short) * (size_t)Npad * HID;
    unsigned short* z    = (unsigned short*)ws;      ws += sizeof(unsigned short) * (size_t)Npad * HID;
    unsigned int*  bucketed = (unsigned int*)ws;     ws += sizeof(unsigned int) * (size_t)E;
    unsigned short* csr  = (unsigned short*)ws;      ws += sizeof(unsigned short) * (size_t)E;

    const int BS = 256;
    const int NBLK_SCAN = (N + 1023) / 1024;

    k_zero_words<<<(N + G * HID + BS - 1) / BS, BS, 0, stream>>>((unsigned int*)indeg, N + G * HID);
    k_hist_count<<<256, BS, 0, stream>>>(dst, indeg, hist, E, NB, CHUNK);
    k_scan1<<<NBLK_SCAN, BS, 0, stream>>>(indeg, offs, blocksum, N);
    k_scan2_aux<<<67, BS, 0, stream>>>(blocksum, NBLK_SCAN, batch, cnt, W2, w2t,
                                       hist, bucket_base, N, G, NB, E);
    k_scan3<<<(N + BS - 1) / BS, BS, 0, stream>>>(offs, blocksum, indeg, dinv, x, xs16, N);
    k_bucket<<<256, BS, 0, stream>>>(src, dst, hist, bucketed, E, NB, CHUNK);
    k_fill2<<<NB, BS, 0, stream>>>(bucketed, bucket_base, offs, csr, N);

    // conv1
    k_gather16<<<(N * 2 + BS - 1) / BS, BS, 0, stream>>>(xs16, offs, indeg, csr, y, N);
    k_gemm1b<<<(N + 7) / 8, BS, 0, stream>>>(y, W1, dinv, b1, h1p, N);

    // conv2 (gather-then-GEMM, pool fused)
    k_gather_z<<<(N * 16 + BS - 1) / BS, BS, 0, stream>>>(h1p, offs, indeg, csr, z, N);
    k_gemm2_pool<<<Npad / 64, BS, 0, stream>>>(z, w2t, dinv, b2, batch, pooled, N);

    // FC head
    k_fc<<<(G * O + BS - 1) / BS, BS, 0, stream>>>(pooled, cnt, Wfc, bfc, out, G, O);
}

// Round 11
// 245.906 us; speedup vs baseline: 1.2173x; 1.2173x over previous
//
#include <hip/hip_runtime.h>
#include <hip/hip_bf16.h>

#define HID 128
#define IN_DIM 16

typedef short bf16x8 __attribute__((ext_vector_type(8)));
typedef float f32x4 __attribute__((ext_vector_type(4)));
typedef unsigned short u16x8 __attribute__((ext_vector_type(8)));

// ---------- bf16 helpers (RNE) ----------
__device__ __forceinline__ unsigned short f2bf(float f) {
    unsigned int u = __float_as_uint(f);
    unsigned int r = (u + 0x7FFFu + ((u >> 16) & 1u)) >> 16;
    return (unsigned short)r;
}
__device__ __forceinline__ float bf2f(unsigned short u) {
    return __uint_as_float(((unsigned int)u) << 16);
}

// ---------------- zero words (indeg [int] + pooled [float], adjacent) ----------------
__global__ __launch_bounds__(256) void k_zero_words(unsigned int* p, int n) {
    int i = blockIdx.x * blockDim.x + threadIdx.x;
    if (i < n) p[i] = 0u;
}

// ---------------- B1: indeg atomics + per-block bucket histogram ----------------
__global__ __launch_bounds__(256) void k_hist_count(const int* __restrict__ dst,
                                                    int* __restrict__ indeg,
                                                    int* __restrict__ hist,
                                                    int E, int NB, int chunk) {
    __shared__ int lh[256];
    for (int i = threadIdx.x; i < NB; i += 256) lh[i] = 0;
    __syncthreads();
    int s0 = blockIdx.x * chunk;
    int e_end = min(E, s0 + chunk);
    for (int e = s0 + threadIdx.x; e < e_end; e += 256) {
        int d = dst[e];
        atomicAdd(&indeg[d], 1);
        atomicAdd(&lh[d >> 8], 1);
    }
    __syncthreads();
    for (int i = threadIdx.x; i < NB; i += 256)
        hist[blockIdx.x * NB + i] = lh[i];   // [blk][b] contiguous per block
}

// ---------------- 2-level exclusive scan over indeg ----------------
__global__ __launch_bounds__(256) void k_scan1(const int* __restrict__ indeg, int* __restrict__ offs,
                                               int* __restrict__ blocksum, int N) {
    __shared__ int sdata[256];
    int base = blockIdx.x * 1024 + threadIdx.x * 4;
    int v0 = (base + 0 < N) ? indeg[base + 0] : 0;
    int v1 = (base + 1 < N) ? indeg[base + 1] : 0;
    int v2 = (base + 2 < N) ? indeg[base + 2] : 0;
    int v3 = (base + 3 < N) ? indeg[base + 3] : 0;
    int s = v0 + v1 + v2 + v3;
    sdata[threadIdx.x] = s;
    __syncthreads();
    for (int off = 1; off < 256; off <<= 1) {
        int t = (threadIdx.x >= off) ? sdata[threadIdx.x - off] : 0;
        __syncthreads();
        sdata[threadIdx.x] += t;
        __syncthreads();
    }
    int excl = sdata[threadIdx.x] - s;
    if (base + 0 < N) offs[base + 0] = excl;  excl += v0;
    if (base + 1 < N) offs[base + 1] = excl;  excl += v1;
    if (base + 2 < N) offs[base + 2] = excl;  excl += v2;
    if (base + 3 < N) offs[base + 3] = excl;
    if (threadIdx.x == 255) blocksum[blockIdx.x] = sdata[255];
}

// ---------------- fused: blocksum scan | per-graph counts | W2T ----------------
__global__ __launch_bounds__(256) void k_scan2_aux(int* __restrict__ blocksum, int nblk,
                                                   const int* __restrict__ batch, float* __restrict__ cnt,
                                                   const float* __restrict__ W2,
                                                   unsigned short* __restrict__ W2T,
                                                   int N, int G) {
    int bid = blockIdx.x;
    if (bid == 0) {
        // wave-parallel exclusive scan of blocksum (nblk <= 64 fast path)
        int lane = threadIdx.x;
        if (lane < 64) {
            if (nblk <= 64) {
                int orig = (lane < nblk) ? blocksum[lane] : 0;
                int v = orig;
                #pragma unroll
                for (int off = 1; off < 64; off <<= 1) {
                    int t = __shfl_up(v, off, 64);
                    if (lane >= off) v += t;
                }
                if (lane < nblk) blocksum[lane] = v - orig;
            } else if (lane == 0) {
                int acc = 0;
                for (int i = 0; i < nblk; ++i) { int t = blocksum[i]; blocksum[i] = acc; acc += t; }
            }
        }
    } else if (bid == 1) {
        int g = threadIdx.x;
        if (g >= G) return;
        int lo = 0, hi = N;
        while (lo < hi) { int mid = (lo + hi) >> 1; if (batch[mid] < g) lo = mid + 1; else hi = mid; }
        int start = lo;
        lo = 0; hi = N;
        while (lo < hi) { int mid = (lo + hi) >> 1; if (batch[mid] <= g) lo = mid + 1; else hi = mid; }
        cnt[g] = (float)(lo - start);
    } else {
        int t = (bid - 2) * 256 + threadIdx.x;   // 0..16383
        int n = t >> 7, k = t & 127;
        W2T[t] = f2bf(W2[(size_t)k * HID + n]);
    }
}

// scan finalize + dinv + xs16 = bf16(dinv*x)  (fused)
__global__ __launch_bounds__(256) void k_scan3(int* __restrict__ offs,
                                               const int* __restrict__ blocksum,
                                               const int* __restrict__ indeg,
                                               float* __restrict__ dinv,
                                               const float* __restrict__ x,
                                               unsigned short* __restrict__ xs16, int N) {
    int i = blockIdx.x * blockDim.x + threadIdx.x;
    if (i >= N) return;
    offs[i] += blocksum[i >> 10];
    float di = rsqrtf(1.0f + (float)indeg[i]);
    dinv[i] = di;
    #pragma unroll
    for (int q = 0; q < 4; ++q) {
        float4 v = *reinterpret_cast<const float4*>(x + (size_t)i * IN_DIM + q * 4);
        ushort4 o4;
        o4.x = f2bf(di * v.x); o4.y = f2bf(di * v.y);
        o4.z = f2bf(di * v.z); o4.w = f2bf(di * v.w);
        *reinterpret_cast<ushort4*>(xs16 + (size_t)i * IN_DIM + q * 4) = o4;
    }
}

// ---------------- B2 (parallel): per-bucket scan of hist column + bucket_base from offs ----------------
// bucket_base[b] = offs_final[b*256]  (edges with dst < b*256). One block per bucket;
// thread t holds hist[t][b]; LDS scan over the 256 producer blocks.
__global__ __launch_bounds__(256) void k_hist_scan(int* __restrict__ hist,
                                                   const int* __restrict__ offs,
                                                   int* __restrict__ bucket_base,
                                                   int NB, int E) {
    __shared__ int sdata[256];
    int b = blockIdx.x;
    int t = threadIdx.x;
    int v = hist[t * NB + b];
    sdata[t] = v;
    __syncthreads();
    for (int off = 1; off < 256; off <<= 1) {
        int tmp = (t >= off) ? sdata[t - off] : 0;
        __syncthreads();
        sdata[t] += tmp;
        __syncthreads();
    }
    int base = offs[b << 8];
    hist[t * NB + b] = sdata[t] - v + base;   // exclusive-over-blk + bucket base
    if (t == 0) {
        bucket_base[b] = base;
        if (b == 0) bucket_base[NB] = E;
    }
}

// ---------------- B3: scatter packed edges into bucket-grouped array ----------------
__global__ __launch_bounds__(256) void k_bucket(const int* __restrict__ src, const int* __restrict__ dst,
                                                const int* __restrict__ hist,
                                                unsigned int* __restrict__ bucketed,
                                                int E, int NB, int chunk) {
    __shared__ int lcur[256];
    for (int i = threadIdx.x; i < NB; i += 256) lcur[i] = hist[blockIdx.x * NB + i];
    __syncthreads();
    int s0 = blockIdx.x * chunk;
    int e_end = min(E, s0 + chunk);
    for (int e = s0 + threadIdx.x; e < e_end; e += 256) {
        int d = dst[e], s = src[e];
        int p = atomicAdd(&lcur[d >> 8], 1);
        bucketed[p] = ((unsigned int)d << 16) | (unsigned int)s;
    }
}

// ---------------- B4: per-bucket CSR fill (one block per 256-node bucket) ----------------
__global__ __launch_bounds__(256) void k_fill2(const unsigned int* __restrict__ bucketed,
                                               const int* __restrict__ bucket_base,
                                               const int* __restrict__ offs,
                                               unsigned short* __restrict__ csr, int N) {
    __shared__ int lcur[256];
    int n0 = blockIdx.x << 8;
    int t = threadIdx.x;
    lcur[t] = (n0 + t < N) ? offs[n0 + t] : 0;
    __syncthreads();
    int bb = bucket_base[blockIdx.x], be = bucket_base[blockIdx.x + 1];
    for (int e = bb + t; e < be; e += 256) {
        unsigned int u = bucketed[e];
        int d = (int)(u >> 16), s = (int)(u & 0xFFFFu);
        int p = atomicAdd(&lcur[d - n0], 1);
        csr[p] = (unsigned short)s;
    }
}

// ---------------- gather16: y[i] = xs16[i] + sum_j xs16[j]   (2 thr/node, ushort8, unroll 8) ----------------
__global__ __launch_bounds__(256) void k_gather16(const unsigned short* __restrict__ xs16,
                                                  const int* __restrict__ offs,
                                                  const int* __restrict__ indeg,
                                                  const unsigned short* __restrict__ csr,
                                                  float* __restrict__ y, int N) {
    int t = blockIdx.x * 256 + threadIdx.x;
    int node = t >> 1;
    if (node >= N) return;
    int c = (t & 1) * 8;
    int base = offs[node], deg = indeg[node];
    u16x8 ow = *reinterpret_cast<const u16x8*>(xs16 + (size_t)node * IN_DIM + c);
    float a[8];
    #pragma unroll
    for (int d = 0; d < 8; ++d) a[d] = bf2f(ow[d]);
    int j = 0;
    for (; j + 8 <= deg; j += 8) {
        int sI[8];
        #pragma unroll
        for (int u = 0; u < 8; ++u) sI[u] = csr[base + j + u];
        u16x8 v[8];
        #pragma unroll
        for (int u = 0; u < 8; ++u)
            v[u] = *reinterpret_cast<const u16x8*>(xs16 + (size_t)sI[u] * IN_DIM + c);
        #pragma unroll
        for (int u = 0; u < 8; ++u)
            #pragma unroll
            for (int d = 0; d < 8; ++d) a[d] += bf2f(v[u][d]);
    }
    for (; j < deg; ++j) {
        int s = csr[base + j];
        u16x8 v = *reinterpret_cast<const u16x8*>(xs16 + (size_t)s * IN_DIM + c);
        #pragma unroll
        for (int d = 0; d < 8; ++d) a[d] += bf2f(v[d]);
    }
    float* yp = y + (size_t)node * IN_DIM + c;
    *reinterpret_cast<float4*>(yp + 0) = make_float4(a[0], a[1], a[2], a[3]);
    *reinterpret_cast<float4*>(yp + 4) = make_float4(a[4], a[5], a[6], a[7]);
}

// ---------------- GEMM1b: h1p[i] = bf16(dinv_i * relu(dinv_i*(y[i]@W1) + b1)) ----------------
__global__ __launch_bounds__(256) void k_gemm1b(const float* __restrict__ y,
                                                const float* __restrict__ W1,
                                                const float* __restrict__ dinv,
                                                const float* __restrict__ b1,
                                                unsigned short* __restrict__ out, int N) {
    __shared__ float Ws[IN_DIM * HID];   // 8 KB
    __shared__ float xs[8][IN_DIM];      // 512 B
    int nb = blockIdx.x * 8;
    for (int i = threadIdx.x * 4; i < IN_DIM * HID; i += 256 * 4)
        *reinterpret_cast<float4*>(&Ws[i]) = *reinterpret_cast<const float4*>(&W1[i]);
    int nrows = min(8, N - nb);
    if (threadIdx.x < 32) {
        int r = threadIdx.x >> 2, c = (threadIdx.x & 3) * 4;
        if (r < nrows)
            *reinterpret_cast<float4*>(&xs[r][c]) =
                *reinterpret_cast<const float4*>(&y[(size_t)(nb + r) * IN_DIM + c]);
    }
    __syncthreads();
    int f = threadIdx.x & 127;
    int g = threadIdx.x >> 7;
    float bb = b1[f];
    for (int r = g; r < nrows; r += 2) {
        int node = nb + r;
        float acc = 0.f;
        #pragma unroll
        for (int k = 0; k < IN_DIM; ++k) acc += xs[r][k] * Ws[k * HID + f];
        float di = dinv[node];
        out[(size_t)node * HID + f] = f2bf(di * fmaxf(di * acc + bb, 0.f));
    }
}

// ---------------- gather_z: z[i] = h1p[i] + sum_j h1p[j]  (16 thr/node, ushort8, unroll 8) ----------------
__global__ __launch_bounds__(256) void k_gather_z(const unsigned short* __restrict__ h1p,
                                                  const int* __restrict__ offs,
                                                  const int* __restrict__ indeg,
                                                  const unsigned short* __restrict__ csr,
                                                  unsigned short* __restrict__ z, int N) {
    int t = blockIdx.x * 256 + threadIdx.x;
    int node = t >> 4;
    if (node >= N) return;
    int c = (t & 15) * 8;
    int base = offs[node], deg = indeg[node];
    u16x8 ow = *reinterpret_cast<const u16x8*>(h1p + (size_t)node * HID + c);
    float a[8];
    #pragma unroll
    for (int d = 0; d < 8; ++d) a[d] = bf2f(ow[d]);
    int j = 0;
    for (; j + 8 <= deg; j += 8) {
        int sI[8];
        #pragma unroll
        for (int u = 0; u < 8; ++u) sI[u] = csr[base + j + u];
        u16x8 v[8];
        #pragma unroll
        for (int u = 0; u < 8; ++u)
            v[u] = *reinterpret_cast<const u16x8*>(h1p + (size_t)sI[u] * HID + c);
        #pragma unroll
        for (int u = 0; u < 8; ++u)
            #pragma unroll
            for (int d = 0; d < 8; ++d) a[d] += bf2f(v[u][d]);
    }
    for (; j < deg; ++j) {
        int s = csr[base + j];
        u16x8 v = *reinterpret_cast<const u16x8*>(h1p + (size_t)s * HID + c);
        #pragma unroll
        for (int d = 0; d < 8; ++d) a[d] += bf2f(v[d]);
    }
    u16x8 o;
    #pragma unroll
    for (int d = 0; d < 8; ++d) o[d] = f2bf(a[d]);
    *reinterpret_cast<u16x8*>(z + (size_t)node * HID + c) = o;
}

// ---------------- GEMM2-MFMA + fused mean-pool ----------------
// mfma_f32_16x16x32_bf16: A row=lane&15,k=(lane>>4)*8+j; D col=lane&15,row=(lane>>4)*4+reg [m89]
__global__ __launch_bounds__(256) void k_gemm2_pool(const unsigned short* __restrict__ z,
                                                    const unsigned short* __restrict__ W2T,
                                                    const float* __restrict__ dinv,
                                                    const float* __restrict__ b2,
                                                    const int* __restrict__ batch,
                                                    float* __restrict__ pooled, int N) {
    __shared__ float pool_s[HID];
    int wave = threadIdx.x >> 6;
    int lane = threadIdx.x & 63;
    int R = blockIdx.x * 64 + wave * 16;
    int lr = lane & 15;
    int lk = (lane >> 4) * 8;
    f32x4 acc[8] = {};
    const unsigned short* arow = z + (size_t)(R + lr) * HID;
    #pragma unroll
    for (int kk = 0; kk < 4; ++kk) {
        bf16x8 a = *reinterpret_cast<const bf16x8*>(arow + kk * 32 + lk);
        #pragma unroll
        for (int cf = 0; cf < 8; ++cf) {
            bf16x8 b = *reinterpret_cast<const bf16x8*>(W2T + (size_t)(cf * 16 + lr) * HID + kk * 32 + lk);
            acc[cf] = __builtin_amdgcn_mfma_f32_16x16x32_bf16(a, b, acc[cf], 0, 0, 0);
        }
    }
    int r0 = (lane >> 4) * 4;
    float di[4];
    int nd[4];
    #pragma unroll
    for (int r = 0; r < 4; ++r) {
        nd[r] = R + r0 + r;
        di[r] = (nd[r] < N) ? dinv[nd[r]] : 0.f;
    }
    int R0 = blockIdx.x * 64;
    int gid0 = batch[min(R0, N - 1)];
    bool single = (R0 + 63 < N) && (batch[R0 + 63] == gid0);
    if (single) {
        if (threadIdx.x < HID) pool_s[threadIdx.x] = 0.f;
        __syncthreads();
        #pragma unroll
        for (int cf = 0; cf < 8; ++cf) {
            float bb = b2[cf * 16 + lr];
            float sc = 0.f;
            #pragma unroll
            for (int r = 0; r < 4; ++r)
                sc += fmaxf(di[r] * acc[cf][r] + bb, 0.f);
            sc += __shfl_xor(sc, 16);
            sc += __shfl_xor(sc, 32);
            if (lane < 16) atomicAdd(&pool_s[cf * 16 + lr], sc);
        }
        __syncthreads();
        if (threadIdx.x < HID)
            atomicAdd(&pooled[(size_t)gid0 * HID + threadIdx.x], pool_s[threadIdx.x]);
    } else {
        #pragma unroll
        for (int r = 0; r < 4; ++r) {
            if (nd[r] < N) {
                int bi = batch[nd[r]];
                #pragma unroll
                for (int cf = 0; cf < 8; ++cf) {
                    float v = fmaxf(di[r] * acc[cf][r] + b2[cf * 16 + lr], 0.f);
                    atomicAdd(&pooled[(size_t)bi * HID + cf * 16 + lr], v);
                }
            }
        }
    }
}

// ---------------- final FC ----------------
__global__ __launch_bounds__(256) void k_fc(const float* __restrict__ pooled,
                                            const float* __restrict__ cnt,
                                            const float* __restrict__ Wfc,
                                            const float* __restrict__ bfc,
                                            float* __restrict__ out, int G, int O) {
    int t = blockIdx.x * blockDim.x + threadIdx.x;
    if (t >= G * O) return;
    int g = t / O, o = t % O;
    float acc = 0.f;
    for (int k = 0; k < HID; ++k) acc += pooled[(size_t)g * HID + k] * Wfc[(size_t)k * O + o];
    out[t] = acc / fmaxf(cnt[g], 1.f) + bfc[o];
}

extern "C" void kernel_launch(void* const* d_in, const int* in_sizes, int n_in,
                              void* d_out, int out_size, void* d_ws, size_t ws_size,
                              hipStream_t stream) {
    const float* x     = (const float*)d_in[0];
    const int*   ei    = (const int*)d_in[1];
    const int*   batch = (const int*)d_in[2];
    const float* W1    = (const float*)d_in[3];
    const float* b1    = (const float*)d_in[4];
    const float* W2    = (const float*)d_in[5];
    const float* b2    = (const float*)d_in[6];
    const float* Wfc   = (const float*)d_in[7];
    const float* bfc   = (const float*)d_in[8];
    float* out = (float*)d_out;

    const int E = in_sizes[1] / 2;
    const int N = in_sizes[2];
    const int O = in_sizes[8];              // 16
    const int G = out_size / O;             // 64
    const int Npad = ((N + 63) / 64) * 64;
    const int NB = (N + 255) >> 8;          // 256-node buckets
    const int CHUNK = (E + 255) / 256;      // edges per B1/B3 block

    const int* src = ei;
    const int* dst = ei + E;

    // workspace layout (all segment starts 16B-aligned for these sizes)
    char* ws = (char*)d_ws;
    int*   indeg  = (int*)ws;                        ws += sizeof(int) * N;
    float* pooled = (float*)ws;                      ws += sizeof(float) * G * HID;
    float* dinv   = (float*)ws;                      ws += sizeof(float) * N;
    int*   offs   = (int*)ws;                        ws += sizeof(int) * N;
    int*   hist   = (int*)ws;                        ws += sizeof(int) * 256 * NB;
    int*   bucket_base = (int*)ws;                   ws += sizeof(int) * ((NB + 4) & ~3);
    int*   blocksum = (int*)ws;                      ws += sizeof(int) * 256;
    float* cnt    = (float*)ws;                      ws += sizeof(float) * G;
    float* y      = (float*)ws;                      ws += sizeof(float) * (size_t)N * IN_DIM;
    unsigned short* xs16 = (unsigned short*)ws;      ws += sizeof(unsigned short) * (size_t)N * IN_DIM;
    unsigned short* w2t  = (unsigned short*)ws;      ws += sizeof(unsigned short) * (size_t)HID * HID;
    unsigned short* h1p  = (unsigned short*)ws;      ws += sizeof(unsigned short) * (size_t)Npad * HID;
    unsigned short* z    = (unsigned short*)ws;      ws += sizeof(unsigned short) * (size_t)Npad * HID;
    unsigned int*  bucketed = (unsigned int*)ws;     ws += sizeof(unsigned int) * (size_t)E;
    unsigned short* csr  = (unsigned short*)ws;      ws += sizeof(unsigned short) * (size_t)E;

    const int BS = 256;
    const int NBLK_SCAN = (N + 1023) / 1024;

    k_zero_words<<<(N + G * HID + BS - 1) / BS, BS, 0, stream>>>((unsigned int*)indeg, N + G * HID);
    k_hist_count<<<256, BS, 0, stream>>>(dst, indeg, hist, E, NB, CHUNK);
    k_scan1<<<NBLK_SCAN, BS, 0, stream>>>(indeg, offs, blocksum, N);
    k_scan2_aux<<<2 + (HID * HID) / BS, BS, 0, stream>>>(blocksum, NBLK_SCAN, batch, cnt, W2, w2t, N, G);
    k_scan3<<<(N + BS - 1) / BS, BS, 0, stream>>>(offs, blocksum, indeg, dinv, x, xs16, N);
    k_hist_scan<<<NB, BS, 0, stream>>>(hist, offs, bucket_base, NB, E);
    k_bucket<<<256, BS, 0, stream>>>(src, dst, hist, bucketed, E, NB, CHUNK);
    k_fill2<<<NB, BS, 0, stream>>>(bucketed, bucket_base, offs, csr, N);

    // conv1
    k_gather16<<<(N * 2 + BS - 1) / BS, BS, 0, stream>>>(xs16, offs, indeg, csr, y, N);
    k_gemm1b<<<(N + 7) / 8, BS, 0, stream>>>(y, W1, dinv, b1, h1p, N);

    // conv2 (gather-then-GEMM, pool fused)
    k_gather_z<<<(N * 16 + BS - 1) / BS, BS, 0, stream>>>(h1p, offs, indeg, csr, z, N);
    k_gemm2_pool<<<Npad / 64, BS, 0, stream>>>(z, w2t, dinv, b2, batch, pooled, N);

    // FC head
    k_fc<<<(G * O + BS - 1) / BS, BS, 0, stream>>>(pooled, cnt, Wfc, bfc, out, G, O);
}

// Round 12
// 212.730 us; speedup vs baseline: 1.4072x; 1.1560x over previous
//
#include <hip/hip_runtime.h>
#include <hip/hip_bf16.h>

#define HID 128
#define IN_DIM 16

typedef short bf16x8 __attribute__((ext_vector_type(8)));
typedef float f32x4 __attribute__((ext_vector_type(4)));
typedef unsigned short u16x8 __attribute__((ext_vector_type(8)));

// ---------- bf16 helpers (RNE) ----------
__device__ __forceinline__ unsigned short f2bf(float f) {
    unsigned int u = __float_as_uint(f);
    unsigned int r = (u + 0x7FFFu + ((u >> 16) & 1u)) >> 16;
    return (unsigned short)r;
}
__device__ __forceinline__ float bf2f(unsigned short u) {
    return __uint_as_float(((unsigned int)u) << 16);
}

// ---------------- B1: per-block bucket histogram (LDS atomics only) ----------------
__global__ __launch_bounds__(256) void k_hist(const int* __restrict__ dst,
                                              int* __restrict__ hist,
                                              int E, int NB, int chunk) {
    __shared__ int lh[256];
    lh[threadIdx.x] = 0;
    __syncthreads();
    int s0 = blockIdx.x * chunk;
    int e_end = min(E, s0 + chunk);
    for (int e = s0 + threadIdx.x; e < e_end; e += 256)
        atomicAdd(&lh[dst[e] >> 8], 1);
    __syncthreads();
    for (int i = threadIdx.x; i < NB; i += 256)
        hist[blockIdx.x * NB + i] = lh[i];   // [blk][b]
}

// ---------------- B2a: column exclusive scan of hist over blk + per-bucket totals ----------------
__global__ __launch_bounds__(256) void k_hist_scan(int* __restrict__ hist,
                                                   int* __restrict__ btot, int NB) {
    __shared__ int sdata[256];
    int b = blockIdx.x, t = threadIdx.x;
    int v = hist[t * NB + b];
    sdata[t] = v;
    __syncthreads();
    for (int off = 1; off < 256; off <<= 1) {
        int tmp = (t >= off) ? sdata[t - off] : 0;
        __syncthreads();
        sdata[t] += tmp;
        __syncthreads();
    }
    hist[t * NB + b] = sdata[t] - v;     // exclusive within column
    if (t == 255) btot[b] = sdata[255];
}

// ---------------- misc: bucket_base scan | per-graph counts | W2T | zero pooled ----------------
__global__ __launch_bounds__(256) void k_misc(const int* __restrict__ btot,
                                              int* __restrict__ bucket_base,
                                              const int* __restrict__ batch, float* __restrict__ cnt,
                                              const float* __restrict__ W2,
                                              unsigned short* __restrict__ W2T,
                                              float* __restrict__ pooled,
                                              int N, int G, int NB, int E) {
    int bid = blockIdx.x;
    int t = threadIdx.x;
    if (bid == 0) {
        // exclusive scan of bucket totals (NB <= 256)
        __shared__ int sdata[256];
        int v = (t < NB) ? btot[t] : 0;
        sdata[t] = v;
        __syncthreads();
        for (int off = 1; off < 256; off <<= 1) {
            int tmp = (t >= off) ? sdata[t - off] : 0;
            __syncthreads();
            sdata[t] += tmp;
            __syncthreads();
        }
        if (t < NB) bucket_base[t] = sdata[t] - v;
        if (t == 0) bucket_base[NB] = E;
    } else if (bid == 1) {
        int g = t;
        if (g >= G) return;
        int lo = 0, hi = N;
        while (lo < hi) { int mid = (lo + hi) >> 1; if (batch[mid] < g) lo = mid + 1; else hi = mid; }
        int start = lo;
        lo = 0; hi = N;
        while (lo < hi) { int mid = (lo + hi) >> 1; if (batch[mid] <= g) lo = mid + 1; else hi = mid; }
        cnt[g] = (float)(lo - start);
    } else if (bid < 66) {
        int i = (bid - 2) * 256 + t;     // 0..16383
        int n = i >> 7, k = i & 127;
        W2T[i] = f2bf(W2[(size_t)k * HID + n]);
    } else {
        int i = (bid - 66) * 256 + t;
        if (i < G * HID) pooled[i] = 0.f;
    }
}

// ---------------- B3: scatter packed edges into bucket-grouped array ----------------
__global__ __launch_bounds__(256) void k_bucket(const int* __restrict__ src, const int* __restrict__ dst,
                                                const int* __restrict__ hist,
                                                const int* __restrict__ bucket_base,
                                                unsigned int* __restrict__ bucketed,
                                                int E, int NB, int chunk) {
    __shared__ int lcur[256];
    for (int i = threadIdx.x; i < NB; i += 256)
        lcur[i] = hist[blockIdx.x * NB + i] + bucket_base[i];
    __syncthreads();
    int s0 = blockIdx.x * chunk;
    int e_end = min(E, s0 + chunk);
    for (int e = s0 + threadIdx.x; e < e_end; e += 256) {
        int d = dst[e], s = src[e];
        int p = atomicAdd(&lcur[d >> 8], 1);
        bucketed[p] = ((unsigned int)(d & 255) << 16) | (unsigned int)s;
    }
}

// ---------------- B4: per-bucket CSR fill + degree/offs/dinv (no global atomics) ----------------
__global__ __launch_bounds__(256) void k_fill3(const unsigned int* __restrict__ bucketed,
                                               const int* __restrict__ bucket_base,
                                               unsigned short* __restrict__ csr,
                                               int* __restrict__ offs,
                                               int* __restrict__ indeg,
                                               float* __restrict__ dinv, int N) {
    __shared__ int lh[256];
    __shared__ int sc[256];
    int b = blockIdx.x, t = threadIdx.x;
    int n0 = b << 8;
    lh[t] = 0;
    __syncthreads();
    int bb = bucket_base[b], be = bucket_base[b + 1];
    for (int e = bb + t; e < be; e += 256)
        atomicAdd(&lh[bucketed[e] >> 16], 1);
    __syncthreads();
    int deg = lh[t];
    sc[t] = deg;
    __syncthreads();
    for (int off = 1; off < 256; off <<= 1) {
        int tmp = (t >= off) ? sc[t - off] : 0;
        __syncthreads();
        sc[t] += tmp;
        __syncthreads();
    }
    int excl = sc[t] - deg + bb;
    int node = n0 + t;
    if (node < N) {
        offs[node] = excl;
        indeg[node] = deg;
        dinv[node] = rsqrtf(1.0f + (float)deg);
    }
    __syncthreads();
    sc[t] = excl;                         // cursor
    __syncthreads();
    for (int e = bb + t; e < be; e += 256) {
        unsigned int u = bucketed[e];
        int p = atomicAdd(&sc[u >> 16], 1);
        csr[p] = (unsigned short)(u & 0xFFFFu);
    }
}

// ---------------- prep: xs16[i] = bf16(dinv_i * x_i) ----------------
__global__ __launch_bounds__(256) void k_prep(const float* __restrict__ x,
                                              const float* __restrict__ dinv,
                                              unsigned short* __restrict__ xs16, int N) {
    int tt = blockIdx.x * 256 + threadIdx.x;
    if (tt >= N * 4) return;
    int node = tt >> 2, q = tt & 3;
    float di = dinv[node];
    float4 v = *reinterpret_cast<const float4*>(x + (size_t)node * IN_DIM + q * 4);
    ushort4 o;
    o.x = f2bf(di * v.x); o.y = f2bf(di * v.y);
    o.z = f2bf(di * v.z); o.w = f2bf(di * v.w);
    *reinterpret_cast<ushort4*>(xs16 + (size_t)node * IN_DIM + q * 4) = o;
}

// ---------------- gather16: y[i] = xs16[i] + sum_j xs16[j]   (2 thr/node, ushort8, unroll 8) ----------------
__global__ __launch_bounds__(256) void k_gather16(const unsigned short* __restrict__ xs16,
                                                  const int* __restrict__ offs,
                                                  const int* __restrict__ indeg,
                                                  const unsigned short* __restrict__ csr,
                                                  float* __restrict__ y, int N) {
    int t = blockIdx.x * 256 + threadIdx.x;
    int node = t >> 1;
    if (node >= N) return;
    int c = (t & 1) * 8;
    int base = offs[node], deg = indeg[node];
    u16x8 ow = *reinterpret_cast<const u16x8*>(xs16 + (size_t)node * IN_DIM + c);
    float a[8];
    #pragma unroll
    for (int d = 0; d < 8; ++d) a[d] = bf2f(ow[d]);
    int j = 0;
    for (; j + 8 <= deg; j += 8) {
        int sI[8];
        #pragma unroll
        for (int u = 0; u < 8; ++u) sI[u] = csr[base + j + u];
        u16x8 v[8];
        #pragma unroll
        for (int u = 0; u < 8; ++u)
            v[u] = *reinterpret_cast<const u16x8*>(xs16 + (size_t)sI[u] * IN_DIM + c);
        #pragma unroll
        for (int u = 0; u < 8; ++u)
            #pragma unroll
            for (int d = 0; d < 8; ++d) a[d] += bf2f(v[u][d]);
    }
    for (; j < deg; ++j) {
        int s = csr[base + j];
        u16x8 v = *reinterpret_cast<const u16x8*>(xs16 + (size_t)s * IN_DIM + c);
        #pragma unroll
        for (int d = 0; d < 8; ++d) a[d] += bf2f(v[d]);
    }
    float* yp = y + (size_t)node * IN_DIM + c;
    *reinterpret_cast<float4*>(yp + 0) = make_float4(a[0], a[1], a[2], a[3]);
    *reinterpret_cast<float4*>(yp + 4) = make_float4(a[4], a[5], a[6], a[7]);
}

// ---------------- GEMM1b: h1p[i] = bf16(dinv_i * relu(dinv_i*(y[i]@W1) + b1)) ----------------
__global__ __launch_bounds__(256) void k_gemm1b(const float* __restrict__ y,
                                                const float* __restrict__ W1,
                                                const float* __restrict__ dinv,
                                                const float* __restrict__ b1,
                                                unsigned short* __restrict__ out, int N) {
    __shared__ float Ws[IN_DIM * HID];   // 8 KB
    __shared__ float xs[8][IN_DIM];      // 512 B
    int nb = blockIdx.x * 8;
    for (int i = threadIdx.x * 4; i < IN_DIM * HID; i += 256 * 4)
        *reinterpret_cast<float4*>(&Ws[i]) = *reinterpret_cast<const float4*>(&W1[i]);
    int nrows = min(8, N - nb);
    if (threadIdx.x < 32) {
        int r = threadIdx.x >> 2, c = (threadIdx.x & 3) * 4;
        if (r < nrows)
            *reinterpret_cast<float4*>(&xs[r][c]) =
                *reinterpret_cast<const float4*>(&y[(size_t)(nb + r) * IN_DIM + c]);
    }
    __syncthreads();
    int f = threadIdx.x & 127;
    int g = threadIdx.x >> 7;
    float bb = b1[f];
    for (int r = g; r < nrows; r += 2) {
        int node = nb + r;
        float acc = 0.f;
        #pragma unroll
        for (int k = 0; k < IN_DIM; ++k) acc += xs[r][k] * Ws[k * HID + f];
        float di = dinv[node];
        out[(size_t)node * HID + f] = f2bf(di * fmaxf(di * acc + bb, 0.f));
    }
}

// ---------------- conv2 fused: LDS-staged gather + MFMA + mean-pool ----------------
// Gather 64 rows of z = h1p[i] + sum_j h1p[j] into swizzled LDS, then
// out2 = relu(dinv*(z@W2)+b2) pooled by graph.  Swizzle: byte ^= (row&7)<<4  [G4].
// mfma_f32_16x16x32_bf16: A row=lane&15,k=(lane>>4)*8+j; D col=lane&15,row=(lane>>4)*4+reg [m89]
__global__ __launch_bounds__(256) void k_conv2_fused(const unsigned short* __restrict__ h1p,
                                                     const int* __restrict__ offs,
                                                     const int* __restrict__ indeg,
                                                     const unsigned short* __restrict__ csr,
                                                     const unsigned short* __restrict__ W2T,
                                                     const float* __restrict__ dinv,
                                                     const float* __restrict__ b2,
                                                     const int* __restrict__ batch,
                                                     float* __restrict__ pooled, int N) {
    __shared__ unsigned short zs[64 * HID];   // 16 KB
    __shared__ float pool_s[HID];
    int t = threadIdx.x;
    int R0 = blockIdx.x * 64;

    // ---- gather phase: 4 thr/node, each covers 32 bf16 (64 B) ----
    {
        int node = R0 + (t >> 2);
        int seg = (t & 3) * 32;
        float a[32];
        #pragma unroll
        for (int i = 0; i < 32; ++i) a[i] = 0.f;
        if (node < N) {
            const unsigned short* own = h1p + (size_t)node * HID + seg;
            #pragma unroll
            for (int q = 0; q < 4; ++q) {
                u16x8 v = *reinterpret_cast<const u16x8*>(own + q * 8);
                #pragma unroll
                for (int d = 0; d < 8; ++d) a[q * 8 + d] = bf2f(v[d]);
            }
            int base = offs[node], deg = indeg[node];
            int j = 0;
            for (; j + 2 <= deg; j += 2) {
                int s0 = csr[base + j], s1 = csr[base + j + 1];
                const unsigned short* p0 = h1p + (size_t)s0 * HID + seg;
                const unsigned short* p1 = h1p + (size_t)s1 * HID + seg;
                u16x8 v[8];
                #pragma unroll
                for (int q = 0; q < 4; ++q) v[q] = *reinterpret_cast<const u16x8*>(p0 + q * 8);
                #pragma unroll
                for (int q = 0; q < 4; ++q) v[4 + q] = *reinterpret_cast<const u16x8*>(p1 + q * 8);
                #pragma unroll
                for (int q = 0; q < 4; ++q)
                    #pragma unroll
                    for (int d = 0; d < 8; ++d)
                        a[q * 8 + d] += bf2f(v[q][d]) + bf2f(v[4 + q][d]);
            }
            if (j < deg) {
                int s0 = csr[base + j];
                const unsigned short* p0 = h1p + (size_t)s0 * HID + seg;
                #pragma unroll
                for (int q = 0; q < 4; ++q) {
                    u16x8 v = *reinterpret_cast<const u16x8*>(p0 + q * 8);
                    #pragma unroll
                    for (int d = 0; d < 8; ++d) a[q * 8 + d] += bf2f(v[d]);
                }
            }
        }
        int row = t >> 2;
        #pragma unroll
        for (int q = 0; q < 4; ++q) {
            u16x8 o;
            #pragma unroll
            for (int d = 0; d < 8; ++d) o[d] = f2bf(a[q * 8 + d]);
            int byte = row * 256 + seg * 2 + q * 16;
            byte ^= (row & 7) << 4;
            *reinterpret_cast<u16x8*>(reinterpret_cast<char*>(zs) + byte) = o;
        }
    }
    __syncthreads();

    // ---- MFMA phase ----
    int wave = t >> 6;
    int lane = t & 63;
    int lr = lane & 15;
    int lkB = (lane >> 4) * 16;          // byte offset of lane's 8 bf16 along k
    f32x4 acc[8] = {};
    #pragma unroll
    for (int kk = 0; kk < 4; ++kk) {
        int abyte = (wave * 16 + lr) * 256 + kk * 64 + lkB;
        abyte ^= (lr & 7) << 4;
        bf16x8 aF = *reinterpret_cast<const bf16x8*>(reinterpret_cast<const char*>(zs) + abyte);
        #pragma unroll
        for (int cf = 0; cf < 8; ++cf) {
            bf16x8 bF = *reinterpret_cast<const bf16x8*>(W2T + (size_t)(cf * 16 + lr) * HID + kk * 32 + (lane >> 4) * 8);
            acc[cf] = __builtin_amdgcn_mfma_f32_16x16x32_bf16(aF, bF, acc[cf], 0, 0, 0);
        }
    }
    int R = R0 + wave * 16;
    int r0 = (lane >> 4) * 4;
    float di[4];
    int nd[4];
    #pragma unroll
    for (int r = 0; r < 4; ++r) {
        nd[r] = R + r0 + r;
        di[r] = (nd[r] < N) ? dinv[nd[r]] : 0.f;
    }
    int gid0 = batch[min(R0, N - 1)];
    bool single = (R0 + 63 < N) && (batch[R0 + 63] == gid0);
    if (single) {
        if (t < HID) pool_s[t] = 0.f;
        __syncthreads();
        #pragma unroll
        for (int cf = 0; cf < 8; ++cf) {
            float bb = b2[cf * 16 + lr];
            float sc = 0.f;
            #pragma unroll
            for (int r = 0; r < 4; ++r)
                sc += fmaxf(di[r] * acc[cf][r] + bb, 0.f);
            sc += __shfl_xor(sc, 16);
            sc += __shfl_xor(sc, 32);
            if (lane < 16) atomicAdd(&pool_s[cf * 16 + lr], sc);
        }
        __syncthreads();
        if (t < HID)
            atomicAdd(&pooled[(size_t)gid0 * HID + t], pool_s[t]);
    } else {
        #pragma unroll
        for (int r = 0; r < 4; ++r) {
            if (nd[r] < N) {
                int bi = batch[nd[r]];
                #pragma unroll
                for (int cf = 0; cf < 8; ++cf) {
                    float v = fmaxf(di[r] * acc[cf][r] + b2[cf * 16 + lr], 0.f);
                    atomicAdd(&pooled[(size_t)bi * HID + cf * 16 + lr], v);
                }
            }
        }
    }
}

// ---------------- final FC ----------------
__global__ __launch_bounds__(256) void k_fc(const float* __restrict__ pooled,
                                            const float* __restrict__ cnt,
                                            const float* __restrict__ Wfc,
                                            const float* __restrict__ bfc,
                                            float* __restrict__ out, int G, int O) {
    int t = blockIdx.x * blockDim.x + threadIdx.x;
    if (t >= G * O) return;
    int g = t / O, o = t % O;
    float acc = 0.f;
    for (int k = 0; k < HID; ++k) acc += pooled[(size_t)g * HID + k] * Wfc[(size_t)k * O + o];
    out[t] = acc / fmaxf(cnt[g], 1.f) + bfc[o];
}

extern "C" void kernel_launch(void* const* d_in, const int* in_sizes, int n_in,
                              void* d_out, int out_size, void* d_ws, size_t ws_size,
                              hipStream_t stream) {
    const float* x     = (const float*)d_in[0];
    const int*   ei    = (const int*)d_in[1];
    const int*   batch = (const int*)d_in[2];
    const float* W1    = (const float*)d_in[3];
    const float* b1    = (const float*)d_in[4];
    const float* W2    = (const float*)d_in[5];
    const float* b2    = (const float*)d_in[6];
    const float* Wfc   = (const float*)d_in[7];
    const float* bfc   = (const float*)d_in[8];
    float* out = (float*)d_out;

    const int E = in_sizes[1] / 2;
    const int N = in_sizes[2];
    const int O = in_sizes[8];              // 16
    const int G = out_size / O;             // 64
    const int Npad = ((N + 63) / 64) * 64;
    const int NB = (N + 255) >> 8;          // 256-node buckets (<=256)
    const int CHUNK = (E + 255) / 256;

    const int* src = ei;
    const int* dst = ei + E;

    // workspace layout
    char* ws = (char*)d_ws;
    int*   indeg  = (int*)ws;                        ws += sizeof(int) * N;
    float* pooled = (float*)ws;                      ws += sizeof(float) * G * HID;
    float* dinv   = (float*)ws;                      ws += sizeof(float) * N;
    int*   offs   = (int*)ws;                        ws += sizeof(int) * N;
    int*   hist   = (int*)ws;                        ws += sizeof(int) * 256 * NB;
    int*   btot   = (int*)ws;                        ws += sizeof(int) * 256;
    int*   bucket_base = (int*)ws;                   ws += sizeof(int) * 260;
    float* cnt    = (float*)ws;                      ws += sizeof(float) * G;
    float* y      = (float*)ws;                      ws += sizeof(float) * (size_t)N * IN_DIM;
    unsigned short* xs16 = (unsigned short*)ws;      ws += sizeof(unsigned short) * (size_t)N * IN_DIM;
    unsigned short* w2t  = (unsigned short*)ws;      ws += sizeof(unsigned short) * (size_t)HID * HID;
    unsigned short* h1p  = (unsigned short*)ws;      ws += sizeof(unsigned short) * (size_t)Npad * HID;
    unsigned int*  bucketed = (unsigned int*)ws;     ws += sizeof(unsigned int) * (size_t)E;
    unsigned short* csr  = (unsigned short*)ws;      ws += sizeof(unsigned short) * (size_t)E;

    const int BS = 256;

    k_hist<<<256, BS, 0, stream>>>(dst, hist, E, NB, CHUNK);
    k_hist_scan<<<NB, BS, 0, stream>>>(hist, btot, NB);
    k_misc<<<66 + (G * HID + BS - 1) / BS, BS, 0, stream>>>(btot, bucket_base, batch, cnt,
                                                            W2, w2t, pooled, N, G, NB, E);
    k_bucket<<<256, BS, 0, stream>>>(src, dst, hist, bucket_base, bucketed, E, NB, CHUNK);
    k_fill3<<<NB, BS, 0, stream>>>(bucketed, bucket_base, csr, offs, indeg, dinv, N);
    k_prep<<<(N * 4 + BS - 1) / BS, BS, 0, stream>>>(x, dinv, xs16, N);

    // conv1
    k_gather16<<<(N * 2 + BS - 1) / BS, BS, 0, stream>>>(xs16, offs, indeg, csr, y, N);
    k_gemm1b<<<(N + 7) / 8, BS, 0, stream>>>(y, W1, dinv, b1, h1p, N);

    // conv2 (fused gather + MFMA + pool)
    k_conv2_fused<<<(N + 63) / 64, BS, 0, stream>>>(h1p, offs, indeg, csr, w2t, dinv, b2,
                                                    batch, pooled, N);

    // FC head
    k_fc<<<(G * O + BS - 1) / BS, BS, 0, stream>>>(pooled, cnt, Wfc, bfc, out, G, O);
}

// Round 14
// 200.611 us; speedup vs baseline: 1.4922x; 1.0604x over previous
//
#include <hip/hip_runtime.h>
#include <hip/hip_bf16.h>

#define HID 128
#define IN_DIM 16

typedef short bf16x8 __attribute__((ext_vector_type(8)));
typedef float f32x4 __attribute__((ext_vector_type(4)));
typedef unsigned short u16x8 __attribute__((ext_vector_type(8)));

// ---------- bf16 helpers (RNE) ----------
__device__ __forceinline__ unsigned short f2bf(float f) {
    unsigned int u = __float_as_uint(f);
    unsigned int r = (u + 0x7FFFu + ((u >> 16) & 1u)) >> 16;
    return (unsigned short)r;
}
__device__ __forceinline__ float bf2f(unsigned short u) {
    return __uint_as_float(((unsigned int)u) << 16);
}

// ---------------- B1: per-block bucket histogram (LDS atomics only) ----------------
__global__ __launch_bounds__(256) void k_hist(const int* __restrict__ dst,
                                              int* __restrict__ hist,
                                              int E, int NB, int chunk) {
    __shared__ int lh[256];
    lh[threadIdx.x] = 0;
    __syncthreads();
    int s0 = blockIdx.x * chunk;
    int e_end = min(E, s0 + chunk);
    for (int e = s0 + threadIdx.x; e < e_end; e += 256)
        atomicAdd(&lh[dst[e] >> 8], 1);
    __syncthreads();
    for (int i = threadIdx.x; i < NB; i += 256)
        hist[blockIdx.x * NB + i] = lh[i];   // [blk][b]
}

// ---------------- B2a: column exclusive scan of hist over blk + per-bucket totals ----------------
__global__ __launch_bounds__(256) void k_hist_scan(int* __restrict__ hist,
                                                   int* __restrict__ btot, int NB) {
    __shared__ int sdata[256];
    int b = blockIdx.x, t = threadIdx.x;
    int v = hist[t * NB + b];
    sdata[t] = v;
    __syncthreads();
    for (int off = 1; off < 256; off <<= 1) {
        int tmp = (t >= off) ? sdata[t - off] : 0;
        __syncthreads();
        sdata[t] += tmp;
        __syncthreads();
    }
    hist[t * NB + b] = sdata[t] - v;     // exclusive within column
    if (t == 255) btot[b] = sdata[255];
}

// ---------------- misc: bucket_base scan | per-graph counts | W2T | zero pooled ----------------
__global__ __launch_bounds__(256) void k_misc(const int* __restrict__ btot,
                                              int* __restrict__ bucket_base,
                                              const int* __restrict__ batch, float* __restrict__ cnt,
                                              const float* __restrict__ W2,
                                              unsigned short* __restrict__ W2T,
                                              float* __restrict__ pooled,
                                              int N, int G, int NB, int E) {
    int bid = blockIdx.x;
    int t = threadIdx.x;
    if (bid == 0) {
        __shared__ int sdata[256];
        int v = (t < NB) ? btot[t] : 0;
        sdata[t] = v;
        __syncthreads();
        for (int off = 1; off < 256; off <<= 1) {
            int tmp = (t >= off) ? sdata[t - off] : 0;
            __syncthreads();
            sdata[t] += tmp;
            __syncthreads();
        }
        if (t < NB) bucket_base[t] = sdata[t] - v;
        if (t == 0) bucket_base[NB] = E;
    } else if (bid == 1) {
        int g = t;
        if (g >= G) return;
        int lo = 0, hi = N;
        while (lo < hi) { int mid = (lo + hi) >> 1; if (batch[mid] < g) lo = mid + 1; else hi = mid; }
        int start = lo;
        lo = 0; hi = N;
        while (lo < hi) { int mid = (lo + hi) >> 1; if (batch[mid] <= g) lo = mid + 1; else hi = mid; }
        cnt[g] = (float)(lo - start);
    } else if (bid < 66) {
        int i = (bid - 2) * 256 + t;     // 0..16383
        int n = i >> 7, k = i & 127;
        W2T[i] = f2bf(W2[(size_t)k * HID + n]);
    } else {
        int i = (bid - 66) * 256 + t;
        if (i < G * HID) pooled[i] = 0.f;
    }
}

// ---------------- B3: scatter packed edges into bucket-grouped array ----------------
__global__ __launch_bounds__(256) void k_bucket(const int* __restrict__ src, const int* __restrict__ dst,
                                                const int* __restrict__ hist,
                                                const int* __restrict__ bucket_base,
                                                unsigned int* __restrict__ bucketed,
                                                int E, int NB, int chunk) {
    __shared__ int lcur[256];
    for (int i = threadIdx.x; i < NB; i += 256)
        lcur[i] = hist[blockIdx.x * NB + i] + bucket_base[i];
    __syncthreads();
    int s0 = blockIdx.x * chunk;
    int e_end = min(E, s0 + chunk);
    for (int e = s0 + threadIdx.x; e < e_end; e += 256) {
        int d = dst[e], s = src[e];
        int p = atomicAdd(&lcur[d >> 8], 1);
        bucketed[p] = ((unsigned int)(d & 255) << 16) | (unsigned int)s;
    }
}

// ---------------- B4: per-bucket CSR fill + degree/offs/dinv (no global atomics) ----------------
__global__ __launch_bounds__(256) void k_fill3(const unsigned int* __restrict__ bucketed,
                                               const int* __restrict__ bucket_base,
                                               unsigned short* __restrict__ csr,
                                               int* __restrict__ offs,
                                               int* __restrict__ indeg,
                                               float* __restrict__ dinv, int N) {
    __shared__ int lh[256];
    __shared__ int sc[256];
    int b = blockIdx.x, t = threadIdx.x;
    int n0 = b << 8;
    lh[t] = 0;
    __syncthreads();
    int bb = bucket_base[b], be = bucket_base[b + 1];
    for (int e = bb + t; e < be; e += 256)
        atomicAdd(&lh[bucketed[e] >> 16], 1);
    __syncthreads();
    int deg = lh[t];
    sc[t] = deg;
    __syncthreads();
    for (int off = 1; off < 256; off <<= 1) {
        int tmp = (t >= off) ? sc[t - off] : 0;
        __syncthreads();
        sc[t] += tmp;
        __syncthreads();
    }
    int excl = sc[t] - deg + bb;
    int node = n0 + t;
    if (node < N) {
        offs[node] = excl;
        indeg[node] = deg;
        dinv[node] = rsqrtf(1.0f + (float)deg);
    }
    __syncthreads();
    sc[t] = excl;                         // cursor
    __syncthreads();
    for (int e = bb + t; e < be; e += 256) {
        unsigned int u = bucketed[e];
        int p = atomicAdd(&sc[u >> 16], 1);
        csr[p] = (unsigned short)(u & 0xFFFFu);
    }
}

// ---------------- prep: xs16[i] = bf16(dinv_i * x_i) ----------------
__global__ __launch_bounds__(256) void k_prep(const float* __restrict__ x,
                                              const float* __restrict__ dinv,
                                              unsigned short* __restrict__ xs16, int N) {
    int tt = blockIdx.x * 256 + threadIdx.x;
    if (tt >= N * 4) return;
    int node = tt >> 2, q = tt & 3;
    float di = dinv[node];
    float4 v = *reinterpret_cast<const float4*>(x + (size_t)node * IN_DIM + q * 4);
    ushort4 o;
    o.x = f2bf(di * v.x); o.y = f2bf(di * v.y);
    o.z = f2bf(di * v.z); o.w = f2bf(di * v.w);
    *reinterpret_cast<ushort4*>(xs16 + (size_t)node * IN_DIM + q * 4) = o;
}

// ---------------- gather16: y[i] = xs16[i] + sum_j xs16[j]   (2 thr/node, ushort8, unroll 8) ----------------
__global__ __launch_bounds__(256) void k_gather16(const unsigned short* __restrict__ xs16,
                                                  const int* __restrict__ offs,
                                                  const int* __restrict__ indeg,
                                                  const unsigned short* __restrict__ csr,
                                                  float* __restrict__ y, int N) {
    int t = blockIdx.x * 256 + threadIdx.x;
    int node = t >> 1;
    if (node >= N) return;
    int c = (t & 1) * 8;
    int base = offs[node], deg = indeg[node];
    u16x8 ow = *reinterpret_cast<const u16x8*>(xs16 + (size_t)node * IN_DIM + c);
    float a[8];
    #pragma unroll
    for (int d = 0; d < 8; ++d) a[d] = bf2f(ow[d]);
    int j = 0;
    for (; j + 8 <= deg; j += 8) {
        int sI[8];
        #pragma unroll
        for (int u = 0; u < 8; ++u) sI[u] = csr[base + j + u];
        u16x8 v[8];
        #pragma unroll
        for (int u = 0; u < 8; ++u)
            v[u] = *reinterpret_cast<const u16x8*>(xs16 + (size_t)sI[u] * IN_DIM + c);
        #pragma unroll
        for (int u = 0; u < 8; ++u)
            #pragma unroll
            for (int d = 0; d < 8; ++d) a[d] += bf2f(v[u][d]);
    }
    for (; j < deg; ++j) {
        int s = csr[base + j];
        u16x8 v = *reinterpret_cast<const u16x8*>(xs16 + (size_t)s * IN_DIM + c);
        #pragma unroll
        for (int d = 0; d < 8; ++d) a[d] += bf2f(v[d]);
    }
    float* yp = y + (size_t)node * IN_DIM + c;
    *reinterpret_cast<float4*>(yp + 0) = make_float4(a[0], a[1], a[2], a[3]);
    *reinterpret_cast<float4*>(yp + 4) = make_float4(a[4], a[5], a[6], a[7]);
}

// ---------------- GEMM1b: h1p[i] = bf16(dinv_i * relu(dinv_i*(y[i]@W1) + b1)) ----------------
__global__ __launch_bounds__(256) void k_gemm1b(const float* __restrict__ y,
                                                const float* __restrict__ W1,
                                                const float* __restrict__ dinv,
                                                const float* __restrict__ b1,
                                                unsigned short* __restrict__ out, int N) {
    __shared__ float Ws[IN_DIM * HID];   // 8 KB
    __shared__ float xs[8][IN_DIM];      // 512 B
    int nb = blockIdx.x * 8;
    for (int i = threadIdx.x * 4; i < IN_DIM * HID; i += 256 * 4)
        *reinterpret_cast<float4*>(&Ws[i]) = *reinterpret_cast<const float4*>(&W1[i]);
    int nrows = min(8, N - nb);
    if (threadIdx.x < 32) {
        int r = threadIdx.x >> 2, c = (threadIdx.x & 3) * 4;
        if (r < nrows)
            *reinterpret_cast<float4*>(&xs[r][c]) =
                *reinterpret_cast<const float4*>(&y[(size_t)(nb + r) * IN_DIM + c]);
    }
    __syncthreads();
    int f = threadIdx.x & 127;
    int g = threadIdx.x >> 7;
    float bb = b1[f];
    for (int r = g; r < nrows; r += 2) {
        int node = nb + r;
        float acc = 0.f;
        #pragma unroll
        for (int k = 0; k < IN_DIM; ++k) acc += xs[r][k] * Ws[k * HID + f];
        float di = dinv[node];
        out[(size_t)node * HID + f] = f2bf(di * fmaxf(di * acc + bb, 0.f));
    }
}

// ---------------- conv2 fused v2: 512 threads, 16 thr/node gather + 8-wave MFMA + pool ----------------
// Swizzle: byte ^= (row&7)<<4 [G4].  MFMA m89 layout.
__global__ __launch_bounds__(512) void k_conv2_fused(const unsigned short* __restrict__ h1p,
                                                     const int* __restrict__ offs,
                                                     const int* __restrict__ indeg,
                                                     const unsigned short* __restrict__ csr,
                                                     const unsigned short* __restrict__ W2T,
                                                     const float* __restrict__ dinv,
                                                     const float* __restrict__ b2,
                                                     const int* __restrict__ batch,
                                                     float* __restrict__ pooled, int N) {
    __shared__ unsigned short zs[64 * HID];   // 16 KB
    __shared__ float pool_s[HID];
    int t = threadIdx.x;
    int R0 = blockIdx.x * 64;

    // ---- gather phase: 16 thr/node (16B per thread per row), 2 passes of 32 nodes ----
    #pragma unroll
    for (int pass = 0; pass < 2; ++pass) {
        int row = pass * 32 + (t >> 4);
        int node = R0 + row;
        int c = (t & 15) * 8;                 // bf16 index in row
        float a[8];
        #pragma unroll
        for (int d = 0; d < 8; ++d) a[d] = 0.f;
        if (node < N) {
            u16x8 ow = *reinterpret_cast<const u16x8*>(h1p + (size_t)node * HID + c);
            #pragma unroll
            for (int d = 0; d < 8; ++d) a[d] = bf2f(ow[d]);
            int base = offs[node], deg = indeg[node];
            int j = 0;
            for (; j + 4 <= deg; j += 4) {
                int s0 = csr[base + j + 0], s1 = csr[base + j + 1];
                int s2 = csr[base + j + 2], s3 = csr[base + j + 3];
                u16x8 v0 = *reinterpret_cast<const u16x8*>(h1p + (size_t)s0 * HID + c);
                u16x8 v1 = *reinterpret_cast<const u16x8*>(h1p + (size_t)s1 * HID + c);
                u16x8 v2 = *reinterpret_cast<const u16x8*>(h1p + (size_t)s2 * HID + c);
                u16x8 v3 = *reinterpret_cast<const u16x8*>(h1p + (size_t)s3 * HID + c);
                #pragma unroll
                for (int d = 0; d < 8; ++d)
                    a[d] += (bf2f(v0[d]) + bf2f(v1[d])) + (bf2f(v2[d]) + bf2f(v3[d]));
            }
            for (; j < deg; ++j) {
                int s = csr[base + j];
                u16x8 v = *reinterpret_cast<const u16x8*>(h1p + (size_t)s * HID + c);
                #pragma unroll
                for (int d = 0; d < 8; ++d) a[d] += bf2f(v[d]);
            }
        }
        u16x8 o;
        #pragma unroll
        for (int d = 0; d < 8; ++d) o[d] = f2bf(a[d]);
        int byte = row * 256 + c * 2;
        byte ^= (row & 7) << 4;
        *reinterpret_cast<u16x8*>(reinterpret_cast<char*>(zs) + byte) = o;
    }
    __syncthreads();

    // ---- MFMA phase: 8 waves; wave = (row-group rg = w>>1) x (cf-half ch = (w&1)*4) ----
    int wave = t >> 6;
    int lane = t & 63;
    int rg = wave >> 1;
    int ch = (wave & 1) * 4;
    int lr = lane & 15;
    int lkB = (lane >> 4) * 16;
    f32x4 acc[4] = {};
    #pragma unroll
    for (int kk = 0; kk < 4; ++kk) {
        int abyte = (rg * 16 + lr) * 256 + kk * 64 + lkB;
        abyte ^= (lr & 7) << 4;
        bf16x8 aF = *reinterpret_cast<const bf16x8*>(reinterpret_cast<const char*>(zs) + abyte);
        #pragma unroll
        for (int cfi = 0; cfi < 4; ++cfi) {
            int col0 = (ch + cfi) * 16;
            bf16x8 bF = *reinterpret_cast<const bf16x8*>(W2T + (size_t)(col0 + lr) * HID + kk * 32 + (lane >> 4) * 8);
            acc[cfi] = __builtin_amdgcn_mfma_f32_16x16x32_bf16(aF, bF, acc[cfi], 0, 0, 0);
        }
    }
    int R = R0 + rg * 16;
    int r0 = (lane >> 4) * 4;
    float di[4];
    int nd[4];
    #pragma unroll
    for (int r = 0; r < 4; ++r) {
        nd[r] = R + r0 + r;
        di[r] = (nd[r] < N) ? dinv[nd[r]] : 0.f;
    }
    int gid0 = batch[min(R0, N - 1)];
    bool single = (R0 + 63 < N) && (batch[R0 + 63] == gid0);
    if (single) {
        if (t < HID) pool_s[t] = 0.f;
        __syncthreads();
        #pragma unroll
        for (int cfi = 0; cfi < 4; ++cfi) {
            int col = (ch + cfi) * 16 + lr;
            float bb = b2[col];
            float sc = 0.f;
            #pragma unroll
            for (int r = 0; r < 4; ++r)
                sc += fmaxf(di[r] * acc[cfi][r] + bb, 0.f);
            sc += __shfl_xor(sc, 16);
            sc += __shfl_xor(sc, 32);
            if (lane < 16) atomicAdd(&pool_s[col], sc);
        }
        __syncthreads();
        if (t < HID)
            atomicAdd(&pooled[(size_t)gid0 * HID + t], pool_s[t]);
    } else {
        #pragma unroll
        for (int r = 0; r < 4; ++r) {
            if (nd[r] < N) {
                int bi = batch[nd[r]];
                #pragma unroll
                for (int cfi = 0; cfi < 4; ++cfi) {
                    int col = (ch + cfi) * 16 + lr;
                    float v = fmaxf(di[r] * acc[cfi][r] + b2[col], 0.f);
                    atomicAdd(&pooled[(size_t)bi * HID + col], v);
                }
            }
        }
    }
}

// ---------------- final FC ----------------
__global__ __launch_bounds__(256) void k_fc(const float* __restrict__ pooled,
                                            const float* __restrict__ cnt,
                                            const float* __restrict__ Wfc,
                                            const float* __restrict__ bfc,
                                            float* __restrict__ out, int G, int O) {
    int t = blockIdx.x * blockDim.x + threadIdx.x;
    if (t >= G * O) return;
    int g = t / O, o = t % O;
    float acc = 0.f;
    for (int k = 0; k < HID; ++k) acc += pooled[(size_t)g * HID + k] * Wfc[(size_t)k * O + o];
    out[t] = acc / fmaxf(cnt[g], 1.f) + bfc[o];
}

extern "C" void kernel_launch(void* const* d_in, const int* in_sizes, int n_in,
                              void* d_out, int out_size, void* d_ws, size_t ws_size,
                              hipStream_t stream) {
    const float* x     = (const float*)d_in[0];
    const int*   ei    = (const int*)d_in[1];
    const int*   batch = (const int*)d_in[2];
    const float* W1    = (const float*)d_in[3];
    const float* b1    = (const float*)d_in[4];
    const float* W2    = (const float*)d_in[5];
    const float* b2    = (const float*)d_in[6];
    const float* Wfc   = (const float*)d_in[7];
    const float* bfc   = (const float*)d_in[8];
    float* out = (float*)d_out;

    const int E = in_sizes[1] / 2;
    const int N = in_sizes[2];
    const int O = in_sizes[8];              // 16
    const int G = out_size / O;             // 64
    const int Npad = ((N + 63) / 64) * 64;
    const int NB = (N + 255) >> 8;          // 256-node buckets (<=256)
    const int CHUNK = (E + 255) / 256;

    const int* src = ei;
    const int* dst = ei + E;

    // workspace layout
    char* ws = (char*)d_ws;
    int*   indeg  = (int*)ws;                        ws += sizeof(int) * N;
    float* pooled = (float*)ws;                      ws += sizeof(float) * G * HID;
    float* dinv   = (float*)ws;                      ws += sizeof(float) * N;
    int*   offs   = (int*)ws;                        ws += sizeof(int) * N;
    int*   hist   = (int*)ws;                        ws += sizeof(int) * 256 * NB;
    int*   btot   = (int*)ws;                        ws += sizeof(int) * 256;
    int*   bucket_base = (int*)ws;                   ws += sizeof(int) * 260;
    float* cnt    = (float*)ws;                      ws += sizeof(float) * G;
    float* y      = (float*)ws;                      ws += sizeof(float) * (size_t)N * IN_DIM;
    unsigned short* xs16 = (unsigned short*)ws;      ws += sizeof(unsigned short) * (size_t)N * IN_DIM;
    unsigned short* w2t  = (unsigned short*)ws;      ws += sizeof(unsigned short) * (size_t)HID * HID;
    unsigned short* h1p  = (unsigned short*)ws;      ws += sizeof(unsigned short) * (size_t)Npad * HID;
    unsigned int*  bucketed = (unsigned int*)ws;     ws += sizeof(unsigned int) * (size_t)E;
    unsigned short* csr  = (unsigned short*)ws;      ws += sizeof(unsigned short) * (size_t)E;

    const int BS = 256;

    k_hist<<<256, BS, 0, stream>>>(dst, hist, E, NB, CHUNK);
    k_hist_scan<<<NB, BS, 0, stream>>>(hist, btot, NB);
    k_misc<<<66 + (G * HID + BS - 1) / BS, BS, 0, stream>>>(btot, bucket_base, batch, cnt,
                                                            W2, w2t, pooled, N, G, NB, E);
    k_bucket<<<256, BS, 0, stream>>>(src, dst, hist, bucket_base, bucketed, E, NB, CHUNK);
    k_fill3<<<NB, BS, 0, stream>>>(bucketed, bucket_base, csr, offs, indeg, dinv, N);
    k_prep<<<(N * 4 + BS - 1) / BS, BS, 0, stream>>>(x, dinv, xs16, N);

    // conv1
    k_gather16<<<(N * 2 + BS - 1) / BS, BS, 0, stream>>>(xs16, offs, indeg, csr, y, N);
    k_gemm1b<<<(N + 7) / 8, BS, 0, stream>>>(y, W1, dinv, b1, h1p, N);

    // conv2 (fused gather + MFMA + pool, 512-thread blocks)
    k_conv2_fused<<<(N + 63) / 64, 512, 0, stream>>>(h1p, offs, indeg, csr, w2t, dinv, b2,
                                                     batch, pooled, N);

    // FC head
    k_fc<<<(G * O + BS - 1) / BS, BS, 0, stream>>>(pooled, cnt, Wfc, bfc, out, G, O);
}